// Round 13
// baseline (189.071 us; speedup 1.0000x reference)
//
#include <hip/hip_runtime.h>

#define BATCH 100000

typedef float v2 __attribute__((ext_vector_type(2)));

__device__ __forceinline__ v2 fma2(v2 a, v2 b, v2 c) { return __builtin_elementwise_fma(a, b, c); }
__device__ __forceinline__ v2 relu2(v2 a) { v2 z = {0.f, 0.f}; return __builtin_elementwise_max(a, z); }
__device__ __forceinline__ v2 splat(float a) { v2 r = {a, a}; return r; }
__device__ __forceinline__ v2 ldv2(const float* p) { return *(const v2*)p; }

// R13: TWO samples per lane (S=2). The R7-R12 plateau (~55 us, VALU busy
// ~24 us) is the per-wave 17 KB SMEM weight stream: ~27 all-or-nothing
// lgkmcnt(0) drains/wave (SMEM returns out-of-order -> only full drains),
// ~600 cyc exposed per sample. Weights are touched ONCE per wave
// regardless of samples/lane, so S=2 halves SMEM bytes + drains PER
// SAMPLE and doubles cross-drain ILP (2 independent sample dataflows).
// 2 lanes per sample; lane t: phi neighbors [8t,8t+8), obs [4t,4t+4)
// (linearity: partial acc, one shfl_xor); rho/psi duplicated across pair.
// R11: LDS weight broadcast worse (LDS-pipe issue ~21 us/CU). s_load wins.
// EMPIRICAL VGPR LAW (R3/R6/R9/R10/R11): arch-VGPR cap = 256/minWavesPerEU.
// S=2 needs ~140 VGPR -> minW MUST be 1 (cap 256); HW bucket 129-256 ->
// 2 waves/SIMD = 8/CU >= offered 6.1/CU, all resident.
// Tripwire: WRITE_SIZE must stay ~781 KB (scratch-spill signature).
__global__ __launch_bounds__(256, 1) void barrier_net(
    const float* __restrict__ x,
    const float* __restrict__ phi_w1, const float* __restrict__ phi_b1,
    const float* __restrict__ phi_w2, const float* __restrict__ phi_b2,
    const float* __restrict__ obs_w1, const float* __restrict__ obs_b1,
    const float* __restrict__ obs_w2, const float* __restrict__ obs_b2,
    const float* __restrict__ rho_w1, const float* __restrict__ rho_b1,
    const float* __restrict__ rho_w2, const float* __restrict__ rho_b2,
    const float* __restrict__ psi_w1, const float* __restrict__ psi_b1,
    const float* __restrict__ psi_w2, const float* __restrict__ psi_b2,
    float2* __restrict__ out)
{
    const int tid = blockIdx.x * 256 + threadIdx.x;
    const int pr = tid >> 1;          // lane-pair index
    const int t  = tid & 1;
    const int s0 = 2 * pr;
    const int s1 = 2 * pr + 1;
    if (s0 >= BATCH) return;
    const float* xr[2];
    xr[0] = x + (size_t)s0 * 85;
    xr[1] = x + (size_t)(s1 < BATCH ? s1 : s0) * 85;   // clamp: safe load, store guarded

    // ---- per-lane slice of BOTH samples: 8 neighbors, 4 observations ----
    float nb[2][8][4];
    const int nbase = 5 + 32 * t;
#pragma unroll
    for (int u = 0; u < 2; ++u)
#pragma unroll
        for (int n = 0; n < 8; ++n)
#pragma unroll
            for (int k = 0; k < 4; ++k)
                nb[u][n][k] = xr[u][nbase + 4 * n + k];

    float ob[2][4][2];
    const int obase = 69 + 8 * t;
#pragma unroll
    for (int u = 0; u < 2; ++u)
#pragma unroll
        for (int o = 0; o < 4; ++o) {
            ob[u][o][0] = xr[u][obase + 2 * o];
            ob[u][o][1] = xr[u][obase + 2 * o + 1];
        }

    float g0[2], g1[2];
#pragma unroll
    for (int u = 0; u < 2; ++u) { g0[u] = xr[u][0]; g1[u] = xr[u][1]; }

    // ---- barrier partials ----
    float bar0[2] = {0.f, 0.f}, bar1[2] = {0.f, 0.f};
#pragma unroll
    for (int u = 0; u < 2; ++u)
#pragma unroll
        for (int n = 0; n < 8; ++n) {
            float p0 = -nb[u][n][0], p1 = -nb[u][n][1];
            float r  = __builtin_amdgcn_sqrtf(fmaf(p0, p0, p1 * p1));
            float sc = 0.01f * __builtin_amdgcn_rcpf(r - 0.2f);
            bar0[u] = fmaf(sc, p0, bar0[u]);
            bar1[u] = fmaf(sc, p1, bar1[u]);
        }

    // ---- acc partial (16 as 8 v2) per sample: each lane half the bias ----
    v2 acc[2][8];
#pragma unroll
    for (int p = 0; p < 8; ++p) {
        v2 b = fma2(splat(8.f), ldv2(phi_b2 + 2 * p),
               fma2(splat(4.f), ldv2(obs_b2 + 2 * p), splat(0.f)));
        acc[0][p] = b; acc[1][p] = b;
    }

    // ---- phi: chunks of 8 h; weight loads CSE'd across the two samples ----
#pragma unroll 2
    for (int c = 0; c < 8; ++c) {
        const int hb = c * 8;
#pragma unroll
        for (int u = 0; u < 2; ++u) {
            v2 hsv[4] = {{0.f,0.f},{0.f,0.f},{0.f,0.f},{0.f,0.f}};
#pragma unroll
            for (int n = 0; n < 8; ++n) {
#pragma unroll
                for (int p = 0; p < 4; ++p) {
                    v2 tv = fma2(splat(nb[u][n][0]), ldv2(phi_w1 + hb + 2 * p),
                            fma2(splat(nb[u][n][1]), ldv2(phi_w1 + 64 + hb + 2 * p),
                            fma2(splat(nb[u][n][2]), ldv2(phi_w1 + 128 + hb + 2 * p),
                            fma2(splat(nb[u][n][3]), ldv2(phi_w1 + 192 + hb + 2 * p),
                                                     ldv2(phi_b1 + hb + 2 * p)))));
                    hsv[p] += relu2(tv);
                }
            }
#pragma unroll
            for (int p = 0; p < 4; ++p) {
                const float* r0 = phi_w2 + (size_t)(hb + 2 * p) * 16;
                v2 hx = splat(hsv[p].x), hy = splat(hsv[p].y);
#pragma unroll
                for (int q = 0; q < 8; ++q)
                    acc[u][q] = fma2(hy, ldv2(r0 + 16 + 2 * q),
                                fma2(hx, ldv2(r0 + 2 * q), acc[u][q]));
            }
        }
    }

    // ---- obs: same chunking ----
#pragma unroll 2
    for (int c = 0; c < 8; ++c) {
        const int hb = c * 8;
#pragma unroll
        for (int u = 0; u < 2; ++u) {
            v2 hsv[4] = {{0.f,0.f},{0.f,0.f},{0.f,0.f},{0.f,0.f}};
#pragma unroll
            for (int o = 0; o < 4; ++o) {
#pragma unroll
                for (int p = 0; p < 4; ++p) {
                    v2 tv = fma2(splat(ob[u][o][0]), ldv2(obs_w1 + hb + 2 * p),
                            fma2(splat(ob[u][o][1]), ldv2(obs_w1 + 64 + hb + 2 * p),
                                                     ldv2(obs_b1 + hb + 2 * p)));
                    hsv[p] += relu2(tv);
                }
            }
#pragma unroll
            for (int p = 0; p < 4; ++p) {
                const float* r0 = obs_w2 + (size_t)(hb + 2 * p) * 16;
                v2 hx = splat(hsv[p].x), hy = splat(hsv[p].y);
#pragma unroll
                for (int q = 0; q < 8; ++q)
                    acc[u][q] = fma2(hy, ldv2(r0 + 16 + 2 * q),
                                fma2(hx, ldv2(r0 + 2 * q), acc[u][q]));
            }
        }
    }

    // ---- pair-sum: acc + barrier ----
#pragma unroll
    for (int u = 0; u < 2; ++u) {
#pragma unroll
        for (int p = 0; p < 8; ++p) {
            acc[u][p].x += __shfl_xor(acc[u][p].x, 1);
            acc[u][p].y += __shfl_xor(acc[u][p].y, 1);
        }
        bar0[u] += __shfl_xor(bar0[u], 1);
        bar1[u] += __shfl_xor(bar1[u], 1);
    }

    // ---- rho: 16 -> 64 -> 2, duplicated across pair, chunked ----
    v2 rr[2];
    rr[0] = ldv2(rho_b2); rr[1] = rr[0];
#pragma unroll 2
    for (int c = 0; c < 8; ++c) {
        const int hb = c * 8;
#pragma unroll
        for (int u = 0; u < 2; ++u) {
            v2 tt[4];
#pragma unroll
            for (int p = 0; p < 4; ++p)
                tt[p] = ldv2(rho_b1 + hb + 2 * p);
#pragma unroll
            for (int j = 0; j < 8; ++j) {
                v2 ax = splat(acc[u][j].x), ay = splat(acc[u][j].y);
                const float* rj0 = rho_w1 + (size_t)(2 * j) * 64 + hb;
                const float* rj1 = rho_w1 + (size_t)(2 * j + 1) * 64 + hb;
#pragma unroll
                for (int p = 0; p < 4; ++p)
                    tt[p] = fma2(ay, ldv2(rj1 + 2 * p),
                            fma2(ax, ldv2(rj0 + 2 * p), tt[p]));
            }
#pragma unroll
            for (int p = 0; p < 4; ++p) {
                v2 w = relu2(tt[p]);
                rr[u] = fma2(splat(w.x), ldv2(rho_w2 + 2 * (hb + 2 * p)), rr[u]);
                rr[u] = fma2(splat(w.y), ldv2(rho_w2 + 2 * (hb + 2 * p) + 2), rr[u]);
            }
        }
    }

    // ---- psi: [r0, r1, g0, g1] -> 64 -> 2, duplicated, chunked ----
    v2 ee[2];
    ee[0] = ldv2(psi_b2); ee[1] = ee[0];
#pragma unroll 2
    for (int c = 0; c < 8; ++c) {
        const int hb = c * 8;
#pragma unroll
        for (int u = 0; u < 2; ++u) {
#pragma unroll
            for (int p = 0; p < 4; ++p) {
                v2 tv = fma2(splat(rr[u].x), ldv2(psi_w1 + hb + 2 * p),
                        fma2(splat(rr[u].y), ldv2(psi_w1 + 64 + hb + 2 * p),
                        fma2(splat(g0[u]),   ldv2(psi_w1 + 128 + hb + 2 * p),
                        fma2(splat(g1[u]),   ldv2(psi_w1 + 192 + hb + 2 * p),
                                             ldv2(psi_b1 + hb + 2 * p)))));
                v2 w = relu2(tv);
                ee[u] = fma2(splat(w.x), ldv2(psi_w2 + 2 * (hb + 2 * p)), ee[u]);
                ee[u] = fma2(splat(w.y), ldv2(psi_w2 + 2 * (hb + 2 * p) + 2), ee[u]);
            }
        }
    }

    if (t == 0) {
        float a00 = tanhf(tanhf(ee[0].x) + bar0[0]);
        float a01 = tanhf(tanhf(ee[0].y) + bar1[0]);
        out[s0] = make_float2(2.f * a00, 2.f * a01);
        if (s1 < BATCH) {
            float a10 = tanhf(tanhf(ee[1].x) + bar0[1]);
            float a11 = tanhf(tanhf(ee[1].y) + bar1[1]);
            out[s1] = make_float2(2.f * a10, 2.f * a11);
        }
    }
}

extern "C" void kernel_launch(void* const* d_in, const int* in_sizes, int n_in,
                              void* d_out, int out_size, void* d_ws, size_t ws_size,
                              hipStream_t stream) {
    // 256 threads = 128 lane-pairs = 256 samples per block
    const int blocks = (BATCH + 255) / 256;
    barrier_net<<<blocks, 256, 0, stream>>>(
        (const float*)d_in[0],
        (const float*)d_in[1],  (const float*)d_in[2],  (const float*)d_in[3],  (const float*)d_in[4],
        (const float*)d_in[5],  (const float*)d_in[6],  (const float*)d_in[7],  (const float*)d_in[8],
        (const float*)d_in[9],  (const float*)d_in[10], (const float*)d_in[11], (const float*)d_in[12],
        (const float*)d_in[13], (const float*)d_in[14], (const float*)d_in[15], (const float*)d_in[16],
        (float2*)d_out);
}